// Round 1
// baseline (5705.473 us; speedup 1.0000x reference)
//
#include <hip/hip_runtime.h>

#define BB 2
#define TT 8
#define CC 64
#define HH 160
#define WW 160
#define HWW (HH*WW)      // 25600
#define RR 16
#define C2 128
#define C4 256
#define NSTEP 7
#define CHW (CC*HWW)     // 1638400
#define EPSV 1e-5f

// ---------------- pool: mean over H,W for frames 0..6 ----------------
__global__ void pool_kernel(const float* __restrict__ feat, float* __restrict__ pool) {
    int idx = blockIdx.x;                 // b*NSTEP*CC + f*CC + c
    int b = idx / (NSTEP * CC);
    int f = (idx / CC) % NSTEP;
    int c = idx % CC;
    const float4* src = (const float4*)(feat + ((size_t)(b * TT + f) * CC + c) * HWW);
    float s = 0.f;
    for (int i = threadIdx.x; i < HWW / 4; i += 256) {
        float4 v = src[i];
        s += v.x + v.y + v.z + v.w;
    }
    __shared__ float sm[256];
    sm[threadIdx.x] = s;
    __syncthreads();
    for (int off = 128; off > 0; off >>= 1) {
        if (threadIdx.x < off) sm[threadIdx.x] += sm[threadIdx.x + off];
        __syncthreads();
    }
    if (threadIdx.x == 0) pool[idx] = sm[0] * (1.0f / HWW);
}

// ---------------- dynamic depthwise weights: z = relu(BN(pool@w1^T)); wd = z@w2^T + b2 ----------------
__global__ void wd_kernel(const float* __restrict__ pool, const float* __restrict__ w1,
                          const float* __restrict__ gamma, const float* __restrict__ beta,
                          const float* __restrict__ mean, const float* __restrict__ var,
                          const float* __restrict__ w2, const float* __restrict__ b2,
                          float* __restrict__ wd) {
    int bf = blockIdx.x;                  // 0..BB*NSTEP-1
    __shared__ float z[RR];
    int tid = threadIdx.x;                // 64 threads
    if (tid < RR) {
        const float* p = pool + bf * CC;
        float s = 0.f;
        for (int c = 0; c < CC; c++) s += p[c] * w1[tid * CC + c];
        s = (s - mean[tid]) * rsqrtf(var[tid] + EPSV) * gamma[tid] + beta[tid];
        z[tid] = s > 0.f ? s : 0.f;
    }
    __syncthreads();
    for (int o = tid; o < CC * 9; o += 64) {
        float s = b2[o];
        #pragma unroll
        for (int r = 0; r < RR; r++) s += z[r] * w2[o * RR + r];
        wd[bf * CC * 9 + o] = s;
    }
}

// ---------------- copy init slice (t=7) into output ----------------
__global__ void copy_init_kernel(const float* __restrict__ feat, float* __restrict__ out) {
    int i = blockIdx.x * 256 + threadIdx.x;   // over BB*CHW/4
    int n4 = CHW / 4;
    int b = i / n4;
    int r = i % n4;
    size_t off = ((size_t)(b * TT + (TT - 1)) * CHW) / 4 + r;
    ((float4*)out)[off] = ((const float4*)feat)[off];
}

// ---------------- dynamic depthwise conv on feat_prop ----------------
__global__ void dyndw_kernel(const float* __restrict__ out, const float* __restrict__ wd,
                             const float* __restrict__ kc_bias, float* __restrict__ fp_buf, int fx) {
    int gi = blockIdx.x * 256 + threadIdx.x;  // BB*CHW threads
    int b = gi / CHW;
    int c = (gi / HWW) % CC;
    int p = gi % HWW;
    int y = p / WW, x = p % WW;
    const float* wp = wd + ((b * NSTEP + fx) * CC + c) * 9;
    const float* s = out + ((size_t)(b * TT + fx + 1) * CC + c) * HWW;
    bool ym = y > 0, yp = y < HH - 1, xm = x > 0, xp = x < WW - 1;
    float acc = kc_bias[c];
    acc += (ym && xm ? s[p - WW - 1] : 0.f) * wp[0];
    acc += (ym       ? s[p - WW    ] : 0.f) * wp[1];
    acc += (ym && xp ? s[p - WW + 1] : 0.f) * wp[2];
    acc += (xm       ? s[p - 1]      : 0.f) * wp[3];
    acc +=             s[p]                 * wp[4];
    acc += (xp       ? s[p + 1]      : 0.f) * wp[5];
    acc += (yp && xm ? s[p + WW - 1] : 0.f) * wp[6];
    acc += (yp       ? s[p + WW    ] : 0.f) * wp[7];
    acc += (yp && xp ? s[p + WW + 1] : 0.f) * wp[8];
    fp_buf[gi] = acc;
}

// ---------------- conv1: 3x3, 128 in (64 from feature frame, 64 from fp_buf) -> 128 out, leaky 0.1 ----------------
// grid: BB * (C2/8) * (HWW/256); 8 out-channels per thread, weights via scalar loads
__global__ void conv1_kernel(const float* __restrict__ feat, const float* __restrict__ fp_buf,
                             const float* __restrict__ w, const float* __restrict__ bias,
                             float* __restrict__ fusion, int fx) {
    int blk = blockIdx.x;
    int pb = blk % (HWW / 256);
    int og = (blk / (HWW / 256)) % (C2 / 8);
    int b  = blk / ((HWW / 256) * (C2 / 8));
    int p = pb * 256 + threadIdx.x;
    int y = p / WW, x = p % WW;
    int oc0 = og * 8;
    float acc[8];
    #pragma unroll
    for (int j = 0; j < 8; j++) acc[j] = 0.f;
    const float* xsrc = feat + (size_t)(b * TT + fx) * CHW;
    const float* fsrc = fp_buf + (size_t)b * CHW;
    bool ym = y > 0, yp = y < HH - 1, xm = x > 0, xp = x < WW - 1;
    for (int ci = 0; ci < C2; ci++) {
        const float* s = (ci < CC) ? (xsrc + (size_t)ci * HWW) : (fsrc + (size_t)(ci - CC) * HWW);
        float v[9];
        v[0] = (ym && xm) ? s[p - WW - 1] : 0.f;
        v[1] =  ym        ? s[p - WW    ] : 0.f;
        v[2] = (ym && xp) ? s[p - WW + 1] : 0.f;
        v[3] =  xm        ? s[p - 1]      : 0.f;
        v[4] =              s[p];
        v[5] =  xp        ? s[p + 1]      : 0.f;
        v[6] = (yp && xm) ? s[p + WW - 1] : 0.f;
        v[7] =  yp        ? s[p + WW    ] : 0.f;
        v[8] = (yp && xp) ? s[p + WW + 1] : 0.f;
        #pragma unroll
        for (int j = 0; j < 8; j++) {
            const float* wj = w + ((size_t)(oc0 + j) * C2 + ci) * 9;
            #pragma unroll
            for (int t = 0; t < 9; t++) acc[j] += v[t] * wj[t];
        }
    }
    #pragma unroll
    for (int j = 0; j < 8; j++) {
        float r = acc[j] + bias[oc0 + j];
        r = (r > 0.f) ? r : 0.1f * r;
        fusion[((size_t)b * C2 + oc0 + j) * HWW + p] = r;
    }
}

// ---------------- pw1: 1x1 conv 64 -> 256 (+bias) ----------------
// grid: BB * (C4/8) * (HWW/256)
__global__ void pw1_kernel(const float* __restrict__ fusion, const float* __restrict__ w,
                           const float* __restrict__ bias, float* __restrict__ u, int half) {
    int blk = blockIdx.x;
    int pb = blk % (HWW / 256);
    int og = (blk / (HWW / 256)) % (C4 / 8);
    int b  = blk / ((HWW / 256) * (C4 / 8));
    int p = pb * 256 + threadIdx.x;
    int oc0 = og * 8;
    const float* src = fusion + ((size_t)b * C2 + half * CC) * HWW;
    float acc[8];
    #pragma unroll
    for (int j = 0; j < 8; j++) acc[j] = 0.f;
    for (int ci = 0; ci < CC; ci++) {
        float vv = src[(size_t)ci * HWW + p];
        const float* wp = w + oc0 * CC + ci;
        #pragma unroll
        for (int j = 0; j < 8; j++) acc[j] += vv * wp[j * CC];
    }
    #pragma unroll
    for (int j = 0; j < 8; j++)
        u[((size_t)b * C4 + oc0 + j) * HWW + p] = acc[j] + bias[oc0 + j];
}

// ---------------- pw2 fused: v = dw3x3(u)+dwb computed on the fly; g = sigmoid(po·v + pob); out (+)= f*g ----------------
// grid: BB * (CC/8) * (HWW/256)
__global__ void pw2_kernel(const float* __restrict__ u, const float* __restrict__ dww,
                           const float* __restrict__ dwb, const float* __restrict__ w,
                           const float* __restrict__ bias, const float* __restrict__ fusion,
                           float* __restrict__ out, int half, int fx, int accum) {
    int blk = blockIdx.x;
    int pb = blk % (HWW / 256);
    int og = (blk / (HWW / 256)) % (CC / 8);
    int b  = blk / ((HWW / 256) * (CC / 8));
    int p = pb * 256 + threadIdx.x;
    int y = p / WW, x = p % WW;
    int oc0 = og * 8;
    bool ym = y > 0, yp = y < HH - 1, xm = x > 0, xp = x < WW - 1;
    float acc[8];
    #pragma unroll
    for (int j = 0; j < 8; j++) acc[j] = 0.f;
    const float* ub = u + (size_t)b * C4 * HWW;
    for (int ci = 0; ci < C4; ci++) {
        const float* s = ub + (size_t)ci * HWW;
        const float* dv = dww + ci * 9;
        float vv = dwb[ci];
        vv += (ym && xm ? s[p - WW - 1] : 0.f) * dv[0];
        vv += (ym       ? s[p - WW    ] : 0.f) * dv[1];
        vv += (ym && xp ? s[p - WW + 1] : 0.f) * dv[2];
        vv += (xm       ? s[p - 1]      : 0.f) * dv[3];
        vv +=             s[p]                 * dv[4];
        vv += (xp       ? s[p + 1]      : 0.f) * dv[5];
        vv += (yp && xm ? s[p + WW - 1] : 0.f) * dv[6];
        vv += (yp       ? s[p + WW    ] : 0.f) * dv[7];
        vv += (yp && xp ? s[p + WW + 1] : 0.f) * dv[8];
        const float* wp = w + oc0 * C4 + ci;
        #pragma unroll
        for (int j = 0; j < 8; j++) acc[j] += vv * wp[j * C4];
    }
    const float* fsrc = fusion + ((size_t)b * C2 + half * CC) * HWW;
    float* o = out + ((size_t)(b * TT + fx) * CC + oc0) * HWW;
    #pragma unroll
    for (int j = 0; j < 8; j++) {
        float g = 1.f / (1.f + __expf(-(acc[j] + bias[oc0 + j])));
        float val = fsrc[(size_t)(oc0 + j) * HWW + p] * g;
        if (accum) o[(size_t)j * HWW + p] += val;
        else       o[(size_t)j * HWW + p] = val;
    }
}

extern "C" void kernel_launch(void* const* d_in, const int* in_sizes, int n_in,
                              void* d_out, int out_size, void* d_ws, size_t ws_size,
                              hipStream_t stream) {
    const float* feat     = (const float*)d_in[0];
    const float* kc_w1    = (const float*)d_in[1];
    const float* kc_g     = (const float*)d_in[2];
    const float* kc_be    = (const float*)d_in[3];
    const float* kc_mu    = (const float*)d_in[4];
    const float* kc_var   = (const float*)d_in[5];
    const float* kc_w2    = (const float*)d_in[6];
    const float* kc_b2    = (const float*)d_in[7];
    const float* kc_bias  = (const float*)d_in[8];
    const float* conv1_w  = (const float*)d_in[9];
    const float* conv1_b  = (const float*)d_in[10];
    const float* pi1_w    = (const float*)d_in[11];
    const float* pi1_b    = (const float*)d_in[12];
    const float* dw1_w    = (const float*)d_in[13];
    const float* dw1_b    = (const float*)d_in[14];
    const float* po1_w    = (const float*)d_in[15];
    const float* po1_b    = (const float*)d_in[16];
    const float* pi2_w    = (const float*)d_in[17];
    const float* pi2_b    = (const float*)d_in[18];
    const float* dw2_w    = (const float*)d_in[19];
    const float* dw2_b    = (const float*)d_in[20];
    const float* po2_w    = (const float*)d_in[21];
    const float* po2_b    = (const float*)d_in[22];
    float* out = (float*)d_out;

    float* ws = (float*)d_ws;
    float* pool   = ws;                       // 896 floats (pad to 1024)
    float* wd     = ws + 1024;                // 8064 floats (pad: next at 16384)
    float* fp_buf = ws + 16384;               // BB*CHW       = 3,276,800
    float* fusion = fp_buf + (size_t)BB * CHW;        // BB*C2*HWW = 6,553,600
    float* u      = fusion + (size_t)BB * C2 * HWW;   // BB*C4*HWW = 13,107,200
    // total ~ 92 MB

    pool_kernel<<<BB * NSTEP * CC, 256, 0, stream>>>(feat, pool);
    wd_kernel<<<BB * NSTEP, 64, 0, stream>>>(pool, kc_w1, kc_g, kc_be, kc_mu, kc_var, kc_w2, kc_b2, wd);
    copy_init_kernel<<<BB * CHW / 4 / 256, 256, 0, stream>>>(feat, out);

    for (int i = 0; i < NSTEP; i++) {
        int fx = NSTEP - 1 - i;   // 6..0: x frame index == output time slot
        dyndw_kernel<<<BB * CHW / 256, 256, 0, stream>>>(out, wd, kc_bias, fp_buf, fx);
        conv1_kernel<<<BB * (C2 / 8) * (HWW / 256), 256, 0, stream>>>(feat, fp_buf, conv1_w, conv1_b, fusion, fx);
        // branch 1
        pw1_kernel<<<BB * (C4 / 8) * (HWW / 256), 256, 0, stream>>>(fusion, pi1_w, pi1_b, u, 0);
        pw2_kernel<<<BB * (CC / 8) * (HWW / 256), 256, 0, stream>>>(u, dw1_w, dw1_b, po1_w, po1_b, fusion, out, 0, fx, 0);
        // branch 2
        pw1_kernel<<<BB * (C4 / 8) * (HWW / 256), 256, 0, stream>>>(fusion, pi2_w, pi2_b, u, 1);
        pw2_kernel<<<BB * (CC / 8) * (HWW / 256), 256, 0, stream>>>(u, dw2_w, dw2_b, po2_w, po2_b, fusion, out, 1, fx, 1);
    }
}

// Round 2
// 1401.035 us; speedup vs baseline: 4.0723x; 4.0723x over previous
//
#include <hip/hip_runtime.h>

typedef __attribute__((ext_vector_type(8))) __bf16 bf16x8;
typedef __attribute__((ext_vector_type(4))) float f32x4;

#define BB 2
#define TT 8
#define CC 64
#define HH 160
#define WW 160
#define HWW 25600
#define RR 16
#define C2 128
#define C4 256
#define NSTEP 7
#define CHW (CC*HWW)
#define EPSV 1e-5f

__device__ __forceinline__ f32x4 mfma16(bf16x8 a, bf16x8 b, f32x4 c) {
    return __builtin_amdgcn_mfma_f32_16x16x32_bf16(a, b, c, 0, 0, 0);
}

// ---------------- pool: mean over H,W for frames 0..6 (fp32 planar input) ----------------
__global__ void pool_kernel(const float* __restrict__ feat, float* __restrict__ pool) {
    int idx = blockIdx.x;                 // b*NSTEP*CC + f*CC + c
    int b = idx / (NSTEP * CC);
    int f = (idx / CC) % NSTEP;
    int c = idx % CC;
    const float4* src = (const float4*)(feat + ((size_t)(b * TT + f) * CC + c) * HWW);
    float s = 0.f;
    for (int i = threadIdx.x; i < HWW / 4; i += 256) {
        float4 v = src[i];
        s += v.x + v.y + v.z + v.w;
    }
    __shared__ float sm[256];
    sm[threadIdx.x] = s;
    __syncthreads();
    for (int off = 128; off > 0; off >>= 1) {
        if (threadIdx.x < off) sm[threadIdx.x] += sm[threadIdx.x + off];
        __syncthreads();
    }
    if (threadIdx.x == 0) pool[idx] = sm[0] * (1.0f / HWW);
}

// ---------------- dynamic depthwise weights -> wdT[bf][t][c] (fp32) ----------------
__global__ void wd_kernel(const float* __restrict__ pool, const float* __restrict__ w1,
                          const float* __restrict__ gamma, const float* __restrict__ beta,
                          const float* __restrict__ mean, const float* __restrict__ var,
                          const float* __restrict__ w2, const float* __restrict__ b2,
                          float* __restrict__ wdT) {
    int bf = blockIdx.x;                  // 0..BB*NSTEP-1
    __shared__ float z[RR];
    int tid = threadIdx.x;                // 64 threads
    if (tid < RR) {
        const float* p = pool + bf * CC;
        float s = 0.f;
        for (int c = 0; c < CC; c++) s += p[c] * w1[tid * CC + c];
        s = (s - mean[tid]) * rsqrtf(var[tid] + EPSV) * gamma[tid] + beta[tid];
        z[tid] = s > 0.f ? s : 0.f;
    }
    __syncthreads();
    for (int o = tid; o < CC * 9; o += 64) {
        float s = b2[o];
        #pragma unroll
        for (int r = 0; r < RR; r++) s += z[r] * w2[o * RR + r];
        int c = o / 9, t = o % 9;
        wdT[bf * 576 + t * CC + c] = s;
    }
}

// ---------------- copy init slice (t=7) fp32 planar into output ----------------
__global__ void copy_init_kernel(const float* __restrict__ feat, float* __restrict__ out) {
    int i = blockIdx.x * 256 + threadIdx.x;   // over BB*CHW/4
    int n4 = CHW / 4;
    int b = i / n4;
    int r = i % n4;
    size_t off = ((size_t)(b * TT + (TT - 1)) * CHW) / 4 + r;
    ((float4*)out)[off] = ((const float4*)feat)[off];
}

// ---------------- prep weights: pack to [N][K] bf16 (+ dwT fp32 [t][c]) ----------------
__global__ void prep_weights(const float* __restrict__ c1w,
                             const float* __restrict__ pi1, const float* __restrict__ pi2,
                             const float* __restrict__ po1, const float* __restrict__ po2,
                             const float* __restrict__ dw1, const float* __restrict__ dw2,
                             __bf16* __restrict__ Bc1,
                             __bf16* __restrict__ Bpi1, __bf16* __restrict__ Bpi2,
                             __bf16* __restrict__ Bpo1, __bf16* __restrict__ Bpo2,
                             float* __restrict__ dwT1, float* __restrict__ dwT2) {
    int idx = blockIdx.x * 256 + threadIdx.x;
    if (idx < 147456) {   // conv1: Bc1[oc][t*128+ic]
        int oc = idx / 1152, k = idx % 1152;
        int t = k >> 7, ic = k & 127;
        Bc1[idx] = (__bf16)c1w[(oc * 128 + ic) * 9 + t];
        return;
    }
    idx -= 147456;
    if (idx < 16384) { Bpi1[idx] = (__bf16)pi1[idx]; return; }
    idx -= 16384;
    if (idx < 16384) { Bpi2[idx] = (__bf16)pi2[idx]; return; }
    idx -= 16384;
    if (idx < 16384) { Bpo1[idx] = (__bf16)po1[idx]; return; }
    idx -= 16384;
    if (idx < 16384) { Bpo2[idx] = (__bf16)po2[idx]; return; }
    idx -= 16384;
    if (idx < 2304) { int t = idx / 256, c = idx % 256; dwT1[t * 256 + c] = dw1[c * 9 + t]; return; }
    idx -= 2304;
    if (idx < 2304) { int t = idx / 256, c = idx % 256; dwT2[t * 256 + c] = dw2[c * 9 + t]; }
}

// ---------------- feature planar fp32 -> pixel-major bf16 [bf][p][64] ----------------
__global__ void featPM_kernel(const float* __restrict__ feat, __bf16* __restrict__ featPM) {
    __shared__ float Lt[64 * 68];
    int bf = blockIdx.x / 400;            // b*TT+f, 0..15
    int p0 = (blockIdx.x % 400) * 64;
    int tid = threadIdx.x;
    int c = tid & 63, half = tid >> 6;
    const float* src = feat + ((size_t)bf * CC + c) * HWW + p0 + half * 16;
    #pragma unroll
    for (int k = 0; k < 16; k++) Lt[(half * 16 + k) * 68 + c] = src[k];
    __syncthreads();
    int cg = tid & 7;
    #pragma unroll
    for (int pass = 0; pass < 2; pass++) {
        int pl = (tid >> 3) + pass * 32;
        bf16x8 o;
        #pragma unroll
        for (int j = 0; j < 8; j++) o[j] = (__bf16)Lt[pl * 68 + cg * 8 + j];
        *(bf16x8*)(featPM + ((size_t)bf * HWW + p0 + pl) * CC + cg * 8) = o;
    }
}

// ---------------- dynamic depthwise conv: src (bf16 PM) -> fpPM (bf16 PM) ----------------
__global__ void dyndw_kernel(const __bf16* __restrict__ src, size_t bstr,
                             const float* __restrict__ wdT, const float* __restrict__ kc_bias,
                             __bf16* __restrict__ fpPM, int fx) {
    int gi = blockIdx.x * 256 + threadIdx.x;   // BB*HWW*8
    int c0 = (gi & 7) * 8;
    int rem = gi >> 3;
    int p = rem % HWW;
    int bb = rem / HWW;
    int py = p / WW, px = p % WW;
    float acc[8];
    float4 k0 = *(const float4*)(kc_bias + c0);
    float4 k1 = *(const float4*)(kc_bias + c0 + 4);
    acc[0]=k0.x; acc[1]=k0.y; acc[2]=k0.z; acc[3]=k0.w;
    acc[4]=k1.x; acc[5]=k1.y; acc[6]=k1.z; acc[7]=k1.w;
    const float* wb = wdT + (size_t)(bb * NSTEP + fx) * 576;
    const __bf16* sb = src + (size_t)bb * bstr;
    const int dyA[9] = {-1,-1,-1,0,0,0,1,1,1};
    const int dxA[9] = {-1,0,1,-1,0,1,-1,0,1};
    #pragma unroll
    for (int t = 0; t < 9; t++) {
        int dy = dyA[t], dx = dxA[t];
        if ((unsigned)(py + dy) < HH && (unsigned)(px + dx) < WW) {
            bf16x8 uv = *(const bf16x8*)(sb + (size_t)(p + dy * WW + dx) * CC + c0);
            float4 w0 = *(const float4*)(wb + t * CC + c0);
            float4 w1 = *(const float4*)(wb + t * CC + c0 + 4);
            acc[0] += (float)uv[0] * w0.x; acc[1] += (float)uv[1] * w0.y;
            acc[2] += (float)uv[2] * w0.z; acc[3] += (float)uv[3] * w0.w;
            acc[4] += (float)uv[4] * w1.x; acc[5] += (float)uv[5] * w1.y;
            acc[6] += (float)uv[6] * w1.z; acc[7] += (float)uv[7] * w1.w;
        }
    }
    bf16x8 o;
    #pragma unroll
    for (int j = 0; j < 8; j++) o[j] = (__bf16)acc[j];
    *(bf16x8*)(fpPM + ((size_t)bb * HWW + p) * CC + c0) = o;
}

// ---------------- conv1 implicit-GEMM: M=128px tile, N=128, K=1152 (tap-major) ----------------
__global__ void conv1_gemm(const __bf16* __restrict__ featPM, const __bf16* __restrict__ fpPM,
                           const __bf16* __restrict__ Bc1, const float* __restrict__ bias,
                           __bf16* __restrict__ fusionPM, int fx) {
    __shared__ __align__(16) __bf16 As[128 * 40];
    __shared__ __align__(16) __bf16 Bs[128 * 40];
    const int tid = threadIdx.x;
    const int bb = blockIdx.x / 200;
    const int p0 = (blockIdx.x % 200) * 128;
    const int i = tid >> 1, h = tid & 1;
    const int p = p0 + i;
    const int py = p / WW, px = p % WW;
    const __bf16* featB = featPM + (size_t)(bb * TT + fx) * HWW * CC;
    const __bf16* fpB   = fpPM + (size_t)bb * HWW * CC;
    const int wv = tid >> 6, lane = tid & 63, lm = lane & 15, lq = lane >> 4;
    f32x4 acc[2][8];
    #pragma unroll
    for (int mt = 0; mt < 2; mt++)
        #pragma unroll
        for (int nt = 0; nt < 8; nt++) acc[mt][nt] = (f32x4){0.f, 0.f, 0.f, 0.f};

    for (int ks = 0; ks < 36; ks++) {
        const int t = ks >> 2, ci0 = (ks & 3) * 32;
        const int dy = t / 3 - 1, dx = t % 3 - 1;
        const bool valid = ((unsigned)(py + dy) < HH) && ((unsigned)(px + dx) < WW);
        uint4 a0 = {0,0,0,0}, a1 = {0,0,0,0};
        if (valid) {
            const __bf16* sp = (ci0 < 64)
                ? featB + (size_t)(p + dy * WW + dx) * CC + ci0
                : fpB   + (size_t)(p + dy * WW + dx) * CC + (ci0 - 64);
            a0 = *(const uint4*)(sp + h * 16);
            a1 = *(const uint4*)(sp + h * 16 + 8);
        }
        const __bf16* bp = Bc1 + (size_t)i * 1152 + ks * 32 + h * 16;
        uint4 w0q = *(const uint4*)(bp);
        uint4 w1q = *(const uint4*)(bp + 8);
        __syncthreads();
        *(uint4*)&As[i * 40 + h * 16]     = a0;
        *(uint4*)&As[i * 40 + h * 16 + 8] = a1;
        *(uint4*)&Bs[i * 40 + h * 16]     = w0q;
        *(uint4*)&Bs[i * 40 + h * 16 + 8] = w1q;
        __syncthreads();
        bf16x8 af0 = *(const bf16x8*)&As[((wv * 2 + 0) * 16 + lm) * 40 + lq * 8];
        bf16x8 af1 = *(const bf16x8*)&As[((wv * 2 + 1) * 16 + lm) * 40 + lq * 8];
        #pragma unroll
        for (int nt = 0; nt < 8; nt++) {
            bf16x8 bf = *(const bf16x8*)&Bs[(nt * 16 + lm) * 40 + lq * 8];
            acc[0][nt] = mfma16(af0, bf, acc[0][nt]);
            acc[1][nt] = mfma16(af1, bf, acc[1][nt]);
        }
    }
    __bf16* ob = fusionPM + (size_t)bb * HWW * C2;
    #pragma unroll
    for (int mt = 0; mt < 2; mt++) {
        #pragma unroll
        for (int nt = 0; nt < 8; nt++) {
            const int oc = nt * 16 + lm;
            const float bs = bias[oc];
            #pragma unroll
            for (int r = 0; r < 4; r++) {
                const int pp = p0 + (wv * 2 + mt) * 16 + lq * 4 + r;
                float v = acc[mt][nt][r] + bs;
                v = v > 0.f ? v : 0.1f * v;
                ob[(size_t)pp * C2 + oc] = (__bf16)v;
            }
        }
    }
}

// ---------------- pw1 GEMM: u = fusion_half @ pi^T + b; M=128, N=128(of 256), K=64 ----------------
__global__ void pw1_gemm(const __bf16* __restrict__ fusionPM, const __bf16* __restrict__ Bpi,
                         const float* __restrict__ bias, __bf16* __restrict__ uPM, int half) {
    __shared__ __align__(16) __bf16 As[128 * 40];
    __shared__ __align__(16) __bf16 Bs[128 * 40];
    const int tid = threadIdx.x;
    const int bb = blockIdx.x / 400;
    const int rem = blockIdx.x % 400;
    const int p0 = (rem >> 1) * 128;
    const int nb = rem & 1;
    const int i = tid >> 1, h = tid & 1;
    const int p = p0 + i;
    const __bf16* fB = fusionPM + (size_t)bb * HWW * C2 + half * CC;
    const int wv = tid >> 6, lane = tid & 63, lm = lane & 15, lq = lane >> 4;
    f32x4 acc[2][8];
    #pragma unroll
    for (int mt = 0; mt < 2; mt++)
        #pragma unroll
        for (int nt = 0; nt < 8; nt++) acc[mt][nt] = (f32x4){0.f, 0.f, 0.f, 0.f};

    #pragma unroll
    for (int ks = 0; ks < 2; ks++) {
        const int ci0 = ks * 32;
        const __bf16* sp = fB + (size_t)p * C2 + ci0 + h * 16;
        uint4 a0 = *(const uint4*)(sp);
        uint4 a1 = *(const uint4*)(sp + 8);
        const __bf16* bp = Bpi + (size_t)(nb * 128 + i) * 64 + ci0 + h * 16;
        uint4 w0q = *(const uint4*)(bp);
        uint4 w1q = *(const uint4*)(bp + 8);
        __syncthreads();
        *(uint4*)&As[i * 40 + h * 16]     = a0;
        *(uint4*)&As[i * 40 + h * 16 + 8] = a1;
        *(uint4*)&Bs[i * 40 + h * 16]     = w0q;
        *(uint4*)&Bs[i * 40 + h * 16 + 8] = w1q;
        __syncthreads();
        bf16x8 af0 = *(const bf16x8*)&As[((wv * 2 + 0) * 16 + lm) * 40 + lq * 8];
        bf16x8 af1 = *(const bf16x8*)&As[((wv * 2 + 1) * 16 + lm) * 40 + lq * 8];
        #pragma unroll
        for (int nt = 0; nt < 8; nt++) {
            bf16x8 bf = *(const bf16x8*)&Bs[(nt * 16 + lm) * 40 + lq * 8];
            acc[0][nt] = mfma16(af0, bf, acc[0][nt]);
            acc[1][nt] = mfma16(af1, bf, acc[1][nt]);
        }
    }
    __bf16* ub = uPM + (size_t)bb * HWW * C4;
    #pragma unroll
    for (int mt = 0; mt < 2; mt++) {
        #pragma unroll
        for (int nt = 0; nt < 8; nt++) {
            const int oc = nb * 128 + nt * 16 + lm;
            const float bs = bias[oc];
            #pragma unroll
            for (int r = 0; r < 4; r++) {
                const int pp = p0 + (wv * 2 + mt) * 16 + lq * 4 + r;
                ub[(size_t)pp * C4 + oc] = (__bf16)(acc[mt][nt][r] + bs);
            }
        }
    }
}

// ---------------- dwv: v = dw3x3(u) + b, bf16 PM -> bf16 PM ----------------
__global__ void dwv_kernel(const __bf16* __restrict__ uPM, const float* __restrict__ dwT,
                           const float* __restrict__ dwb, __bf16* __restrict__ vPM) {
    int gi = blockIdx.x * 256 + threadIdx.x;    // BB*HWW*32
    int c0 = (gi & 31) * 8;
    int rem = gi >> 5;
    int p = rem % HWW;
    int bb = rem / HWW;
    int py = p / WW, px = p % WW;
    float acc[8];
    float4 b0 = *(const float4*)(dwb + c0);
    float4 b1 = *(const float4*)(dwb + c0 + 4);
    acc[0]=b0.x; acc[1]=b0.y; acc[2]=b0.z; acc[3]=b0.w;
    acc[4]=b1.x; acc[5]=b1.y; acc[6]=b1.z; acc[7]=b1.w;
    const __bf16* ub = uPM + (size_t)bb * HWW * C4;
    const int dyA[9] = {-1,-1,-1,0,0,0,1,1,1};
    const int dxA[9] = {-1,0,1,-1,0,1,-1,0,1};
    #pragma unroll
    for (int t = 0; t < 9; t++) {
        int dy = dyA[t], dx = dxA[t];
        if ((unsigned)(py + dy) < HH && (unsigned)(px + dx) < WW) {
            bf16x8 uv = *(const bf16x8*)(ub + (size_t)(p + dy * WW + dx) * C4 + c0);
            float4 w0 = *(const float4*)(dwT + t * C4 + c0);
            float4 w1 = *(const float4*)(dwT + t * C4 + c0 + 4);
            acc[0] += (float)uv[0] * w0.x; acc[1] += (float)uv[1] * w0.y;
            acc[2] += (float)uv[2] * w0.z; acc[3] += (float)uv[3] * w0.w;
            acc[4] += (float)uv[4] * w1.x; acc[5] += (float)uv[5] * w1.y;
            acc[6] += (float)uv[6] * w1.z; acc[7] += (float)uv[7] * w1.w;
        }
    }
    bf16x8 o;
    #pragma unroll
    for (int j = 0; j < 8; j++) o[j] = (__bf16)acc[j];
    *(bf16x8*)(vPM + ((size_t)bb * HWW + p) * C4 + c0) = o;
}

// ---------------- pw2 GEMM + gate epilogue: M=128, N=64, K=256 ----------------
__global__ void pw2_gemm(const __bf16* __restrict__ vPM, const __bf16* __restrict__ Bpo,
                         const float* __restrict__ bias, const __bf16* __restrict__ fusionPM,
                         float* __restrict__ out, __bf16* __restrict__ outPM,
                         int half, int fx, int accum) {
    __shared__ __align__(16) __bf16 As[128 * 40];
    __shared__ __align__(16) __bf16 Bs[64 * 40];
    const int tid = threadIdx.x;
    const int bb = blockIdx.x / 200;
    const int p0 = (blockIdx.x % 200) * 128;
    const int i = tid >> 1, h = tid & 1;
    const int p = p0 + i;
    const __bf16* vB = vPM + (size_t)bb * HWW * C4;
    const int wv = tid >> 6, lane = tid & 63, lm = lane & 15, lq = lane >> 4;
    f32x4 acc[2][4];
    #pragma unroll
    for (int mt = 0; mt < 2; mt++)
        #pragma unroll
        for (int nt = 0; nt < 4; nt++) acc[mt][nt] = (f32x4){0.f, 0.f, 0.f, 0.f};

    for (int ks = 0; ks < 8; ks++) {
        const int ci0 = ks * 32;
        const __bf16* sp = vB + (size_t)p * C4 + ci0 + h * 16;
        uint4 a0 = *(const uint4*)(sp);
        uint4 a1 = *(const uint4*)(sp + 8);
        uint4 w0q = {0,0,0,0}, w1q = {0,0,0,0};
        if (tid < 128) {
            const __bf16* bp = Bpo + (size_t)i * C4 + ci0 + h * 16;
            w0q = *(const uint4*)(bp);
            w1q = *(const uint4*)(bp + 8);
        }
        __syncthreads();
        *(uint4*)&As[i * 40 + h * 16]     = a0;
        *(uint4*)&As[i * 40 + h * 16 + 8] = a1;
        if (tid < 128) {
            *(uint4*)&Bs[i * 40 + h * 16]     = w0q;
            *(uint4*)&Bs[i * 40 + h * 16 + 8] = w1q;
        }
        __syncthreads();
        bf16x8 af0 = *(const bf16x8*)&As[((wv * 2 + 0) * 16 + lm) * 40 + lq * 8];
        bf16x8 af1 = *(const bf16x8*)&As[((wv * 2 + 1) * 16 + lm) * 40 + lq * 8];
        #pragma unroll
        for (int nt = 0; nt < 4; nt++) {
            bf16x8 bf = *(const bf16x8*)&Bs[(nt * 16 + lm) * 40 + lq * 8];
            acc[0][nt] = mfma16(af0, bf, acc[0][nt]);
            acc[1][nt] = mfma16(af1, bf, acc[1][nt]);
        }
    }
    const __bf16* fB = fusionPM + (size_t)bb * HWW * C2 + half * CC;
    __bf16* opB = outPM + (size_t)bb * HWW * CC;
    #pragma unroll
    for (int mt = 0; mt < 2; mt++) {
        #pragma unroll
        for (int nt = 0; nt < 4; nt++) {
            const int oc = nt * 16 + lm;
            const float bs = bias[oc];
            #pragma unroll
            for (int r = 0; r < 4; r++) {
                const int pp = p0 + (wv * 2 + mt) * 16 + lq * 4 + r;
                float g = 1.f / (1.f + __expf(-(acc[mt][nt][r] + bs)));
                float f = (float)fB[(size_t)pp * C2 + oc];
                float val = f * g;
                size_t oi = ((size_t)(bb * TT + fx) * CC + oc) * HWW + pp;
                if (accum) {
                    val += out[oi];
                    out[oi] = val;
                    opB[(size_t)pp * CC + oc] = (__bf16)val;
                } else {
                    out[oi] = val;
                }
            }
        }
    }
}

extern "C" void kernel_launch(void* const* d_in, const int* in_sizes, int n_in,
                              void* d_out, int out_size, void* d_ws, size_t ws_size,
                              hipStream_t stream) {
    const float* feat     = (const float*)d_in[0];
    const float* kc_w1    = (const float*)d_in[1];
    const float* kc_g     = (const float*)d_in[2];
    const float* kc_be    = (const float*)d_in[3];
    const float* kc_mu    = (const float*)d_in[4];
    const float* kc_var   = (const float*)d_in[5];
    const float* kc_w2    = (const float*)d_in[6];
    const float* kc_b2    = (const float*)d_in[7];
    const float* kc_bias  = (const float*)d_in[8];
    const float* conv1_w  = (const float*)d_in[9];
    const float* conv1_b  = (const float*)d_in[10];
    const float* pi1_w    = (const float*)d_in[11];
    const float* pi1_b    = (const float*)d_in[12];
    const float* dw1_w    = (const float*)d_in[13];
    const float* dw1_b    = (const float*)d_in[14];
    const float* po1_w    = (const float*)d_in[15];
    const float* po1_b    = (const float*)d_in[16];
    const float* pi2_w    = (const float*)d_in[17];
    const float* pi2_b    = (const float*)d_in[18];
    const float* dw2_w    = (const float*)d_in[19];
    const float* dw2_b    = (const float*)d_in[20];
    const float* po2_w    = (const float*)d_in[21];
    const float* po2_b    = (const float*)d_in[22];
    float* out = (float*)d_out;

    char* W = (char*)d_ws;
    __bf16* featPM   = (__bf16*)W; W += (size_t)BB * TT * HWW * CC * 2;   // 52,428,800
    __bf16* fpPM     = (__bf16*)W; W += (size_t)BB * HWW * CC * 2;        //  6,553,600
    __bf16* fusionPM = (__bf16*)W; W += (size_t)BB * HWW * C2 * 2;        // 13,107,200
    __bf16* uPM      = (__bf16*)W; W += (size_t)BB * HWW * C4 * 2;        // 26,214,400
    __bf16* vPM      = (__bf16*)W; W += (size_t)BB * HWW * C4 * 2;        // 26,214,400
    __bf16* outPM    = (__bf16*)W; W += (size_t)BB * HWW * CC * 2;        //  6,553,600
    __bf16* Bc1      = (__bf16*)W; W += 294912;
    __bf16* Bpi1     = (__bf16*)W; W += 32768;
    __bf16* Bpi2     = (__bf16*)W; W += 32768;
    __bf16* Bpo1     = (__bf16*)W; W += 32768;
    __bf16* Bpo2     = (__bf16*)W; W += 32768;
    float*  dwT1     = (float*)W;  W += 9216;
    float*  dwT2     = (float*)W;  W += 9216;
    float*  poolb    = (float*)W;  W += 4096;
    float*  wdT      = (float*)W;  W += 32256;   // total ~131.6 MB

    prep_weights<<<850, 256, 0, stream>>>(conv1_w, pi1_w, pi2_w, po1_w, po2_w, dw1_w, dw2_w,
                                          Bc1, Bpi1, Bpi2, Bpo1, Bpo2, dwT1, dwT2);
    featPM_kernel<<<BB * TT * 400, 256, 0, stream>>>(feat, featPM);
    pool_kernel<<<BB * NSTEP * CC, 256, 0, stream>>>(feat, poolb);
    wd_kernel<<<BB * NSTEP, 64, 0, stream>>>(poolb, kc_w1, kc_g, kc_be, kc_mu, kc_var, kc_w2, kc_b2, wdT);
    copy_init_kernel<<<BB * CHW / 4 / 256, 256, 0, stream>>>(feat, out);

    for (int i = 0; i < NSTEP; i++) {
        int fx = NSTEP - 1 - i;   // 6..0
        const __bf16* src = (fx == NSTEP - 1) ? (featPM + (size_t)(TT - 1) * HWW * CC) : outPM;
        size_t bstr = (fx == NSTEP - 1) ? (size_t)TT * HWW * CC : (size_t)HWW * CC;
        dyndw_kernel<<<BB * HWW * 8 / 256, 256, 0, stream>>>(src, bstr, wdT, kc_bias, fpPM, fx);
        conv1_gemm<<<BB * 200, 256, 0, stream>>>(featPM, fpPM, Bc1, conv1_b, fusionPM, fx);
        // branch 1
        pw1_gemm<<<BB * 400, 256, 0, stream>>>(fusionPM, Bpi1, pi1_b, uPM, 0);
        dwv_kernel<<<BB * HWW * 32 / 256, 256, 0, stream>>>(uPM, dwT1, dw1_b, vPM);
        pw2_gemm<<<BB * 200, 256, 0, stream>>>(vPM, Bpo1, po1_b, fusionPM, out, outPM, 0, fx, 0);
        // branch 2
        pw1_gemm<<<BB * 400, 256, 0, stream>>>(fusionPM, Bpi2, pi2_b, uPM, 1);
        dwv_kernel<<<BB * HWW * 32 / 256, 256, 0, stream>>>(uPM, dwT2, dw2_b, vPM);
        pw2_gemm<<<BB * 200, 256, 0, stream>>>(vPM, Bpo2, po2_b, fusionPM, out, outPM, 1, fx, 1);
    }
}

// Round 3
// 1146.670 us; speedup vs baseline: 4.9757x; 1.2218x over previous
//
#include <hip/hip_runtime.h>

typedef __attribute__((ext_vector_type(8))) __bf16 bf16x8;
typedef __attribute__((ext_vector_type(4))) float f32x4;

#define BB 2
#define TT 8
#define CC 64
#define HH 160
#define WW 160
#define HWW 25600
#define RR 16
#define C2 128
#define C4 256
#define C8 512
#define NSTEP 7
#define CHW (CC*HWW)
#define EPSV 1e-5f

__device__ __forceinline__ f32x4 mfma16(bf16x8 a, bf16x8 b, f32x4 c) {
    return __builtin_amdgcn_mfma_f32_16x16x32_bf16(a, b, c, 0, 0, 0);
}

// ---------------- pool: mean over H,W for frames 0..6 (fp32 planar input) ----------------
__global__ void pool_kernel(const float* __restrict__ feat, float* __restrict__ pool) {
    int idx = blockIdx.x;                 // b*NSTEP*CC + f*CC + c
    int b = idx / (NSTEP * CC);
    int f = (idx / CC) % NSTEP;
    int c = idx % CC;
    const float4* src = (const float4*)(feat + ((size_t)(b * TT + f) * CC + c) * HWW);
    float s = 0.f;
    for (int i = threadIdx.x; i < HWW / 4; i += 256) {
        float4 v = src[i];
        s += v.x + v.y + v.z + v.w;
    }
    __shared__ float sm[256];
    sm[threadIdx.x] = s;
    __syncthreads();
    for (int off = 128; off > 0; off >>= 1) {
        if (threadIdx.x < off) sm[threadIdx.x] += sm[threadIdx.x + off];
        __syncthreads();
    }
    if (threadIdx.x == 0) pool[idx] = sm[0] * (1.0f / HWW);
}

// ---------------- dynamic depthwise weights -> wdT[bf][t][c] (fp32) ----------------
__global__ void wd_kernel(const float* __restrict__ pool, const float* __restrict__ w1,
                          const float* __restrict__ gamma, const float* __restrict__ beta,
                          const float* __restrict__ mean, const float* __restrict__ var,
                          const float* __restrict__ w2, const float* __restrict__ b2,
                          float* __restrict__ wdT) {
    int bf = blockIdx.x;                  // 0..BB*NSTEP-1
    __shared__ float z[RR];
    int tid = threadIdx.x;                // 64 threads
    if (tid < RR) {
        const float* p = pool + bf * CC;
        float s = 0.f;
        for (int c = 0; c < CC; c++) s += p[c] * w1[tid * CC + c];
        s = (s - mean[tid]) * rsqrtf(var[tid] + EPSV) * gamma[tid] + beta[tid];
        z[tid] = s > 0.f ? s : 0.f;
    }
    __syncthreads();
    for (int o = tid; o < CC * 9; o += 64) {
        float s = b2[o];
        #pragma unroll
        for (int r = 0; r < RR; r++) s += z[r] * w2[o * RR + r];
        int c = o / 9, t = o % 9;
        wdT[bf * 576 + t * CC + c] = s;
    }
}

// ---------------- copy init slice (t=7) fp32 planar into output ----------------
__global__ void copy_init_kernel(const float* __restrict__ feat, float* __restrict__ out) {
    int i = blockIdx.x * 256 + threadIdx.x;   // over BB*CHW/4
    int n4 = CHW / 4;
    int b = i / n4;
    int r = i % n4;
    size_t off = ((size_t)(b * TT + (TT - 1)) * CHW) / 4 + r;
    ((float4*)out)[off] = ((const float4*)feat)[off];
}

// ---------------- prep weights: pack to [N][K] bf16 (+ dwT12 fp32 [t][c512], dwb12) ----------------
__global__ void prep_weights(const float* __restrict__ c1w,
                             const float* __restrict__ pi1, const float* __restrict__ pi2,
                             const float* __restrict__ po1, const float* __restrict__ po2,
                             const float* __restrict__ dw1, const float* __restrict__ dw2,
                             const float* __restrict__ dw1b, const float* __restrict__ dw2b,
                             __bf16* __restrict__ Bc1,
                             __bf16* __restrict__ Bpi1, __bf16* __restrict__ Bpi2,
                             __bf16* __restrict__ Bpo1, __bf16* __restrict__ Bpo2,
                             float* __restrict__ dwT12, float* __restrict__ dwb12) {
    int idx = blockIdx.x * 256 + threadIdx.x;
    if (idx < 147456) {   // conv1: Bc1[oc][t*128+ic]
        int oc = idx / 1152, k = idx % 1152;
        int t = k >> 7, ic = k & 127;
        Bc1[idx] = (__bf16)c1w[(oc * 128 + ic) * 9 + t];
        return;
    }
    idx -= 147456;
    if (idx < 16384) { Bpi1[idx] = (__bf16)pi1[idx]; return; }
    idx -= 16384;
    if (idx < 16384) { Bpi2[idx] = (__bf16)pi2[idx]; return; }
    idx -= 16384;
    if (idx < 16384) { Bpo1[idx] = (__bf16)po1[idx]; return; }
    idx -= 16384;
    if (idx < 16384) { Bpo2[idx] = (__bf16)po2[idx]; return; }
    idx -= 16384;
    if (idx < 4608) {   // dwT12[t][c512]
        int t = idx / 512, c = idx % 512;
        dwT12[t * C8 + c] = (c < 256) ? dw1[c * 9 + t] : dw2[(c - 256) * 9 + t];
        return;
    }
    idx -= 4608;
    if (idx < 512) { dwb12[idx] = (idx < 256) ? dw1b[idx] : dw2b[idx - 256]; }
}

// ---------------- feature planar fp32 -> pixel-major bf16 [bf][p][64] ----------------
__global__ void featPM_kernel(const float* __restrict__ feat, __bf16* __restrict__ featPM) {
    __shared__ float Lt[64 * 68];
    int bf = blockIdx.x / 400;            // b*TT+f, 0..15
    int p0 = (blockIdx.x % 400) * 64;
    int tid = threadIdx.x;
    int c = tid & 63, half = tid >> 6;
    const float* src = feat + ((size_t)bf * CC + c) * HWW + p0 + half * 16;
    #pragma unroll
    for (int k = 0; k < 16; k++) Lt[(half * 16 + k) * 68 + c] = src[k];
    __syncthreads();
    int cg = tid & 7;
    #pragma unroll
    for (int pass = 0; pass < 2; pass++) {
        int pl = (tid >> 3) + pass * 32;
        bf16x8 o;
        #pragma unroll
        for (int j = 0; j < 8; j++) o[j] = (__bf16)Lt[pl * 68 + cg * 8 + j];
        *(bf16x8*)(featPM + ((size_t)bf * HWW + p0 + pl) * CC + cg * 8) = o;
    }
}

// ---------------- dynamic depthwise conv: src (bf16 PM) -> fpPM (bf16 PM) ----------------
__global__ void dyndw_kernel(const __bf16* __restrict__ src, size_t bstr,
                             const float* __restrict__ wdT, const float* __restrict__ kc_bias,
                             __bf16* __restrict__ fpPM, int fx) {
    int gi = blockIdx.x * 256 + threadIdx.x;   // BB*HWW*8
    int c0 = (gi & 7) * 8;
    int rem = gi >> 3;
    int p = rem % HWW;
    int bb = rem / HWW;
    int py = p / WW, px = p % WW;
    float acc[8];
    float4 k0 = *(const float4*)(kc_bias + c0);
    float4 k1 = *(const float4*)(kc_bias + c0 + 4);
    acc[0]=k0.x; acc[1]=k0.y; acc[2]=k0.z; acc[3]=k0.w;
    acc[4]=k1.x; acc[5]=k1.y; acc[6]=k1.z; acc[7]=k1.w;
    const float* wb = wdT + (size_t)(bb * NSTEP + fx) * 576;
    const __bf16* sb = src + (size_t)bb * bstr;
    const int dyA[9] = {-1,-1,-1,0,0,0,1,1,1};
    const int dxA[9] = {-1,0,1,-1,0,1,-1,0,1};
    #pragma unroll
    for (int t = 0; t < 9; t++) {
        int dy = dyA[t], dx = dxA[t];
        if ((unsigned)(py + dy) < HH && (unsigned)(px + dx) < WW) {
            bf16x8 uv = *(const bf16x8*)(sb + (size_t)(p + dy * WW + dx) * CC + c0);
            float4 w0 = *(const float4*)(wb + t * CC + c0);
            float4 w1 = *(const float4*)(wb + t * CC + c0 + 4);
            acc[0] += (float)uv[0] * w0.x; acc[1] += (float)uv[1] * w0.y;
            acc[2] += (float)uv[2] * w0.z; acc[3] += (float)uv[3] * w0.w;
            acc[4] += (float)uv[4] * w1.x; acc[5] += (float)uv[5] * w1.y;
            acc[6] += (float)uv[6] * w1.z; acc[7] += (float)uv[7] * w1.w;
        }
    }
    bf16x8 o;
    #pragma unroll
    for (int j = 0; j < 8; j++) o[j] = (__bf16)acc[j];
    *(bf16x8*)(fpPM + ((size_t)bb * HWW + p) * CC + c0) = o;
}

// ---------------- conv1 implicit-GEMM: M=128px tile, N=128, K=1152 (tap-major) ----------------
__global__ void conv1_gemm(const __bf16* __restrict__ featPM, const __bf16* __restrict__ fpPM,
                           const __bf16* __restrict__ Bc1, const float* __restrict__ bias,
                           __bf16* __restrict__ fusionPM, int fx) {
    __shared__ __align__(16) __bf16 As[128 * 40];
    __shared__ __align__(16) __bf16 Bs[128 * 40];
    const int tid = threadIdx.x;
    const int bb = blockIdx.x / 200;
    const int p0 = (blockIdx.x % 200) * 128;
    const int i = tid >> 1, h = tid & 1;
    const int p = p0 + i;
    const int py = p / WW, px = p % WW;
    const __bf16* featB = featPM + (size_t)(bb * TT + fx) * HWW * CC;
    const __bf16* fpB   = fpPM + (size_t)bb * HWW * CC;
    const int wv = tid >> 6, lane = tid & 63, lm = lane & 15, lq = lane >> 4;
    f32x4 acc[2][8];
    #pragma unroll
    for (int mt = 0; mt < 2; mt++)
        #pragma unroll
        for (int nt = 0; nt < 8; nt++) acc[mt][nt] = (f32x4){0.f, 0.f, 0.f, 0.f};

    for (int ks = 0; ks < 36; ks++) {
        const int t = ks >> 2, ci0 = (ks & 3) * 32;
        const int dy = t / 3 - 1, dx = t % 3 - 1;
        const bool valid = ((unsigned)(py + dy) < HH) && ((unsigned)(px + dx) < WW);
        uint4 a0 = {0,0,0,0}, a1 = {0,0,0,0};
        if (valid) {
            const __bf16* sp = (ci0 < 64)
                ? featB + (size_t)(p + dy * WW + dx) * CC + ci0
                : fpB   + (size_t)(p + dy * WW + dx) * CC + (ci0 - 64);
            a0 = *(const uint4*)(sp + h * 16);
            a1 = *(const uint4*)(sp + h * 16 + 8);
        }
        const __bf16* bp = Bc1 + (size_t)i * 1152 + ks * 32 + h * 16;
        uint4 w0q = *(const uint4*)(bp);
        uint4 w1q = *(const uint4*)(bp + 8);
        __syncthreads();
        *(uint4*)&As[i * 40 + h * 16]     = a0;
        *(uint4*)&As[i * 40 + h * 16 + 8] = a1;
        *(uint4*)&Bs[i * 40 + h * 16]     = w0q;
        *(uint4*)&Bs[i * 40 + h * 16 + 8] = w1q;
        __syncthreads();
        bf16x8 af0 = *(const bf16x8*)&As[((wv * 2 + 0) * 16 + lm) * 40 + lq * 8];
        bf16x8 af1 = *(const bf16x8*)&As[((wv * 2 + 1) * 16 + lm) * 40 + lq * 8];
        #pragma unroll
        for (int nt = 0; nt < 8; nt++) {
            bf16x8 bf = *(const bf16x8*)&Bs[(nt * 16 + lm) * 40 + lq * 8];
            acc[0][nt] = mfma16(af0, bf, acc[0][nt]);
            acc[1][nt] = mfma16(af1, bf, acc[1][nt]);
        }
    }
    __bf16* ob = fusionPM + (size_t)bb * HWW * C2;
    #pragma unroll
    for (int mt = 0; mt < 2; mt++) {
        #pragma unroll
        for (int nt = 0; nt < 8; nt++) {
            const int oc = nt * 16 + lm;
            const float bs = bias[oc];
            #pragma unroll
            for (int r = 0; r < 4; r++) {
                const int pp = p0 + (wv * 2 + mt) * 16 + lq * 4 + r;
                float v = acc[mt][nt][r] + bs;
                v = v > 0.f ? v : 0.1f * v;
                ob[(size_t)pp * C2 + oc] = (__bf16)v;
            }
        }
    }
}

// ---------------- pw1 fused both branches: u12 = fusion_half @ pi^T + b; per block N=128 of 512 ----------------
// grid: BB * 200 * 4  (nb: branch = nb>>1, sub-half = nb&1)
__global__ void pw1_gemm(const __bf16* __restrict__ fusionPM,
                         const __bf16* __restrict__ Bpi1, const __bf16* __restrict__ Bpi2,
                         const float* __restrict__ pi1b, const float* __restrict__ pi2b,
                         __bf16* __restrict__ u12PM) {
    __shared__ __align__(16) __bf16 As[128 * 40];
    __shared__ __align__(16) __bf16 Bs[128 * 40];
    const int tid = threadIdx.x;
    const int bb = blockIdx.x / 800;
    const int rem = blockIdx.x % 800;
    const int p0 = (rem >> 2) * 128;
    const int nb = rem & 3;
    const int br = nb >> 1, ns = nb & 1;
    const __bf16* Bpi = br ? Bpi2 : Bpi1;
    const float* bias = br ? pi2b : pi1b;
    const int i = tid >> 1, h = tid & 1;
    const int p = p0 + i;
    const __bf16* fB = fusionPM + (size_t)bb * HWW * C2 + br * CC;
    const int wv = tid >> 6, lane = tid & 63, lm = lane & 15, lq = lane >> 4;
    f32x4 acc[2][8];
    #pragma unroll
    for (int mt = 0; mt < 2; mt++)
        #pragma unroll
        for (int nt = 0; nt < 8; nt++) acc[mt][nt] = (f32x4){0.f, 0.f, 0.f, 0.f};

    #pragma unroll
    for (int ks = 0; ks < 2; ks++) {
        const int ci0 = ks * 32;
        const __bf16* sp = fB + (size_t)p * C2 + ci0 + h * 16;
        uint4 a0 = *(const uint4*)(sp);
        uint4 a1 = *(const uint4*)(sp + 8);
        const __bf16* bp = Bpi + (size_t)(ns * 128 + i) * 64 + ci0 + h * 16;
        uint4 w0q = *(const uint4*)(bp);
        uint4 w1q = *(const uint4*)(bp + 8);
        __syncthreads();
        *(uint4*)&As[i * 40 + h * 16]     = a0;
        *(uint4*)&As[i * 40 + h * 16 + 8] = a1;
        *(uint4*)&Bs[i * 40 + h * 16]     = w0q;
        *(uint4*)&Bs[i * 40 + h * 16 + 8] = w1q;
        __syncthreads();
        bf16x8 af0 = *(const bf16x8*)&As[((wv * 2 + 0) * 16 + lm) * 40 + lq * 8];
        bf16x8 af1 = *(const bf16x8*)&As[((wv * 2 + 1) * 16 + lm) * 40 + lq * 8];
        #pragma unroll
        for (int nt = 0; nt < 8; nt++) {
            bf16x8 bf = *(const bf16x8*)&Bs[(nt * 16 + lm) * 40 + lq * 8];
            acc[0][nt] = mfma16(af0, bf, acc[0][nt]);
            acc[1][nt] = mfma16(af1, bf, acc[1][nt]);
        }
    }
    __bf16* ub = u12PM + (size_t)bb * HWW * C8;
    #pragma unroll
    for (int mt = 0; mt < 2; mt++) {
        #pragma unroll
        for (int nt = 0; nt < 8; nt++) {
            const int ocl = ns * 128 + nt * 16 + lm;      // within branch's 256
            const int oc = br * 256 + ocl;                // within 512
            const float bs = bias[ocl];
            #pragma unroll
            for (int r = 0; r < 4; r++) {
                const int pp = p0 + (wv * 2 + mt) * 16 + lq * 4 + r;
                ub[(size_t)pp * C8 + oc] = (__bf16)(acc[mt][nt][r] + bs);
            }
        }
    }
}

// ---------------- dwv fused: v12 = dw3x3(u12) + b over 512 channels ----------------
__global__ void dwv_kernel(const __bf16* __restrict__ u12PM, const float* __restrict__ dwT12,
                           const float* __restrict__ dwb12, __bf16* __restrict__ v12PM) {
    int gi = blockIdx.x * 256 + threadIdx.x;    // BB*HWW*64
    int c0 = (gi & 63) * 8;
    int rem = gi >> 6;
    int p = rem % HWW;
    int bb = rem / HWW;
    int py = p / WW, px = p % WW;
    float acc[8];
    float4 b0 = *(const float4*)(dwb12 + c0);
    float4 b1 = *(const float4*)(dwb12 + c0 + 4);
    acc[0]=b0.x; acc[1]=b0.y; acc[2]=b0.z; acc[3]=b0.w;
    acc[4]=b1.x; acc[5]=b1.y; acc[6]=b1.z; acc[7]=b1.w;
    const __bf16* ub = u12PM + (size_t)bb * HWW * C8;
    const int dyA[9] = {-1,-1,-1,0,0,0,1,1,1};
    const int dxA[9] = {-1,0,1,-1,0,1,-1,0,1};
    #pragma unroll
    for (int t = 0; t < 9; t++) {
        int dy = dyA[t], dx = dxA[t];
        if ((unsigned)(py + dy) < HH && (unsigned)(px + dx) < WW) {
            bf16x8 uv = *(const bf16x8*)(ub + (size_t)(p + dy * WW + dx) * C8 + c0);
            float4 w0 = *(const float4*)(dwT12 + t * C8 + c0);
            float4 w1 = *(const float4*)(dwT12 + t * C8 + c0 + 4);
            acc[0] += (float)uv[0] * w0.x; acc[1] += (float)uv[1] * w0.y;
            acc[2] += (float)uv[2] * w0.z; acc[3] += (float)uv[3] * w0.w;
            acc[4] += (float)uv[4] * w1.x; acc[5] += (float)uv[5] * w1.y;
            acc[6] += (float)uv[6] * w1.z; acc[7] += (float)uv[7] * w1.w;
        }
    }
    bf16x8 o;
    #pragma unroll
    for (int j = 0; j < 8; j++) o[j] = (__bf16)acc[j];
    *(bf16x8*)(v12PM + ((size_t)bb * HWW + p) * C8 + c0) = o;
}

// ---------------- pw2 fused both branches + gate epilogue: M=128, N=64, K=512 (split 2x256) ----------------
__global__ void pw2_gemm(const __bf16* __restrict__ v12PM,
                         const __bf16* __restrict__ Bpo1, const __bf16* __restrict__ Bpo2,
                         const float* __restrict__ pob1, const float* __restrict__ pob2,
                         const __bf16* __restrict__ fusionPM,
                         float* __restrict__ out, __bf16* __restrict__ outPM, int fx) {
    __shared__ __align__(16) __bf16 As[128 * 40];
    __shared__ __align__(16) __bf16 Bs[64 * 40];
    const int tid = threadIdx.x;
    const int bb = blockIdx.x / 200;
    const int p0 = (blockIdx.x % 200) * 128;
    const int i = tid >> 1, h = tid & 1;
    const int p = p0 + i;
    const __bf16* vB = v12PM + (size_t)bb * HWW * C8;
    const int wv = tid >> 6, lane = tid & 63, lm = lane & 15, lq = lane >> 4;
    f32x4 acc[2][2][4];    // [branch][mt][nt]
    #pragma unroll
    for (int br = 0; br < 2; br++)
        #pragma unroll
        for (int mt = 0; mt < 2; mt++)
            #pragma unroll
            for (int nt = 0; nt < 4; nt++) acc[br][mt][nt] = (f32x4){0.f, 0.f, 0.f, 0.f};

    for (int ks = 0; ks < 16; ks++) {
        const int ci0 = ks * 32;              // over 512
        const int br = ks >> 3;
        const __bf16* sp = vB + (size_t)p * C8 + ci0 + h * 16;
        uint4 a0 = *(const uint4*)(sp);
        uint4 a1 = *(const uint4*)(sp + 8);
        uint4 w0q = {0,0,0,0}, w1q = {0,0,0,0};
        if (tid < 128) {
            const __bf16* Bpo = br ? Bpo2 : Bpo1;
            const __bf16* bp = Bpo + (size_t)i * C4 + (ci0 & 255) + h * 16;
            w0q = *(const uint4*)(bp);
            w1q = *(const uint4*)(bp + 8);
        }
        __syncthreads();
        *(uint4*)&As[i * 40 + h * 16]     = a0;
        *(uint4*)&As[i * 40 + h * 16 + 8] = a1;
        if (tid < 128) {
            *(uint4*)&Bs[i * 40 + h * 16]     = w0q;
            *(uint4*)&Bs[i * 40 + h * 16 + 8] = w1q;
        }
        __syncthreads();
        bf16x8 af0 = *(const bf16x8*)&As[((wv * 2 + 0) * 16 + lm) * 40 + lq * 8];
        bf16x8 af1 = *(const bf16x8*)&As[((wv * 2 + 1) * 16 + lm) * 40 + lq * 8];
        #pragma unroll
        for (int nt = 0; nt < 4; nt++) {
            bf16x8 bf = *(const bf16x8*)&Bs[(nt * 16 + lm) * 40 + lq * 8];
            acc[br][0][nt] = mfma16(af0, bf, acc[br][0][nt]);
            acc[br][1][nt] = mfma16(af1, bf, acc[br][1][nt]);
        }
    }
    const __bf16* fB = fusionPM + (size_t)bb * HWW * C2;
    __bf16* opB = outPM + (size_t)bb * HWW * CC;
    #pragma unroll
    for (int mt = 0; mt < 2; mt++) {
        #pragma unroll
        for (int nt = 0; nt < 4; nt++) {
            const int oc = nt * 16 + lm;
            const float bs1 = pob1[oc];
            const float bs2 = pob2[oc];
            #pragma unroll
            for (int r = 0; r < 4; r++) {
                const int pp = p0 + (wv * 2 + mt) * 16 + lq * 4 + r;
                float g1 = 1.f / (1.f + __expf(-(acc[0][mt][nt][r] + bs1)));
                float g2 = 1.f / (1.f + __expf(-(acc[1][mt][nt][r] + bs2)));
                float f1 = (float)fB[(size_t)pp * C2 + oc];
                float f2 = (float)fB[(size_t)pp * C2 + CC + oc];
                float val = f1 * g1 + f2 * g2;
                out[((size_t)(bb * TT + fx) * CC + oc) * HWW + pp] = val;
                opB[(size_t)pp * CC + oc] = (__bf16)val;
            }
        }
    }
}

extern "C" void kernel_launch(void* const* d_in, const int* in_sizes, int n_in,
                              void* d_out, int out_size, void* d_ws, size_t ws_size,
                              hipStream_t stream) {
    const float* feat     = (const float*)d_in[0];
    const float* kc_w1    = (const float*)d_in[1];
    const float* kc_g     = (const float*)d_in[2];
    const float* kc_be    = (const float*)d_in[3];
    const float* kc_mu    = (const float*)d_in[4];
    const float* kc_var   = (const float*)d_in[5];
    const float* kc_w2    = (const float*)d_in[6];
    const float* kc_b2    = (const float*)d_in[7];
    const float* kc_bias  = (const float*)d_in[8];
    const float* conv1_w  = (const float*)d_in[9];
    const float* conv1_b  = (const float*)d_in[10];
    const float* pi1_w    = (const float*)d_in[11];
    const float* pi1_b    = (const float*)d_in[12];
    const float* dw1_w    = (const float*)d_in[13];
    const float* dw1_b    = (const float*)d_in[14];
    const float* po1_w    = (const float*)d_in[15];
    const float* po1_b    = (const float*)d_in[16];
    const float* pi2_w    = (const float*)d_in[17];
    const float* pi2_b    = (const float*)d_in[18];
    const float* dw2_w    = (const float*)d_in[19];
    const float* dw2_b    = (const float*)d_in[20];
    const float* po2_w    = (const float*)d_in[21];
    const float* po2_b    = (const float*)d_in[22];
    float* out = (float*)d_out;

    char* W = (char*)d_ws;
    __bf16* featPM   = (__bf16*)W; W += (size_t)BB * TT * HWW * CC * 2;   // 52.4 MB
    __bf16* fpPM     = (__bf16*)W; W += (size_t)BB * HWW * CC * 2;        //  6.6 MB
    __bf16* fusionPM = (__bf16*)W; W += (size_t)BB * HWW * C2 * 2;        // 13.1 MB
    __bf16* u12PM    = (__bf16*)W; W += (size_t)BB * HWW * C8 * 2;        // 52.4 MB
    __bf16* v12PM    = (__bf16*)W; W += (size_t)BB * HWW * C8 * 2;        // 52.4 MB
    __bf16* outPM    = (__bf16*)W; W += (size_t)BB * HWW * CC * 2;        //  6.6 MB
    __bf16* Bc1      = (__bf16*)W; W += 294912;
    __bf16* Bpi1     = (__bf16*)W; W += 32768;
    __bf16* Bpi2     = (__bf16*)W; W += 32768;
    __bf16* Bpo1     = (__bf16*)W; W += 32768;
    __bf16* Bpo2     = (__bf16*)W; W += 32768;
    float*  dwT12    = (float*)W;  W += 18432;
    float*  dwb12    = (float*)W;  W += 2048;
    float*  poolb    = (float*)W;  W += 4096;
    float*  wdT      = (float*)W;  W += 32256;   // total ~184 MB

    prep_weights<<<852, 256, 0, stream>>>(conv1_w, pi1_w, pi2_w, po1_w, po2_w, dw1_w, dw2_w,
                                          dw1_b, dw2_b,
                                          Bc1, Bpi1, Bpi2, Bpo1, Bpo2, dwT12, dwb12);
    featPM_kernel<<<BB * TT * 400, 256, 0, stream>>>(feat, featPM);
    pool_kernel<<<BB * NSTEP * CC, 256, 0, stream>>>(feat, poolb);
    wd_kernel<<<BB * NSTEP, 64, 0, stream>>>(poolb, kc_w1, kc_g, kc_be, kc_mu, kc_var, kc_w2, kc_b2, wdT);
    copy_init_kernel<<<BB * CHW / 4 / 256, 256, 0, stream>>>(feat, out);

    for (int i = 0; i < NSTEP; i++) {
        int fx = NSTEP - 1 - i;   // 6..0
        const __bf16* src = (fx == NSTEP - 1) ? (featPM + (size_t)(TT - 1) * HWW * CC) : outPM;
        size_t bstr = (fx == NSTEP - 1) ? (size_t)TT * HWW * CC : (size_t)HWW * CC;
        dyndw_kernel<<<BB * HWW * 8 / 256, 256, 0, stream>>>(src, bstr, wdT, kc_bias, fpPM, fx);
        conv1_gemm<<<BB * 200, 256, 0, stream>>>(featPM, fpPM, Bc1, conv1_b, fusionPM, fx);
        pw1_gemm<<<BB * 800, 256, 0, stream>>>(fusionPM, Bpi1, Bpi2, pi1_b, pi2_b, u12PM);
        dwv_kernel<<<BB * HWW * 64 / 256, 256, 0, stream>>>(u12PM, dwT12, dwb12, v12PM);
        pw2_gemm<<<BB * 200, 256, 0, stream>>>(v12PM, Bpo1, Bpo2, po1_b, po2_b, fusionPM, out, outPM, fx);
    }
}